// Round 1
// baseline (168.515 us; speedup 1.0000x reference)
//
#include <hip/hip_runtime.h>
#include <math.h>

#define NLM   1024      // landmarks per batch
#define NB    2         // batches
#define OPS   40        // coarse grid size per axis
#define DIM   128       // output volume size per axis
#define OPS3  (OPS*OPS*OPS)
#define DIM3  (DIM*DIM*DIM)

// ---------------------------------------------------------------------------
// ws layout (all float4-aligned):
//   A      : float4[NB*NLM]   @ byte 0       (cx,cy,cz,|c|^2)
//   V      : float4[NB*NLM]   @ byte 32768   (vx,vy,vz,0)
//   coarse : float4[NB*OPS3]  @ byte 65536   (flow0,flow1,flow2,0) per cell
// total = 65536 + 2*64000*16 = 2,113,536 bytes
// ---------------------------------------------------------------------------

__global__ __launch_bounds__(256)
void prep_kernel(const float* __restrict__ coords, const float* __restrict__ offs,
                 float4* __restrict__ A, float4* __restrict__ V) {
    int i = blockIdx.x * blockDim.x + threadIdx.x;   // b*NLM + n
    if (i >= NB * NLM) return;
    float ox = offs[3*i+0], oy = offs[3*i+1], oz = offs[3*i+2];
    float cx = coords[3*i+0] + ox;
    float cy = coords[3*i+1] + oy;
    float cz = coords[3*i+2] + oz;
    A[i] = make_float4(cx, cy, cz, cx*cx + cy*cy + cz*cz);
    V[i] = make_float4(-ox, -oy, -oz, 0.f);
}

// One thread per coarse cell. Coarse cell (p,q,r) -> coordinate
// (lin40[r], lin40[q], lin40[p]) per the reference's permute chain.
__global__ __launch_bounds__(128)
void coarse_kernel(const float4* __restrict__ A, const float4* __restrict__ V,
                   float4* __restrict__ C) {
    __shared__ float4 sA[NLM];
    __shared__ float4 sV[NLM];
    const int b = blockIdx.y;
    for (int t = threadIdx.x; t < NLM; t += 128) {
        sA[t] = A[b*NLM + t];
        sV[t] = V[b*NLM + t];
    }
    __syncthreads();

    const int g = blockIdx.x * 128 + threadIdx.x;    // 0..63999
    const int p = g / (OPS*OPS);
    const int q = (g / OPS) % OPS;
    const int r = g % OPS;

    const float step = 2.f / (OPS - 1);
    const float gx = -1.f + step * r;   // component 0
    const float gy = -1.f + step * q;   // component 1
    const float gz = -1.f + step * p;   // component 2
    const float g2 = gx*gx + gy*gy + gz*gz;

    float S = 0.f, vx = 0.f, vy = 0.f, vz = 0.f;
    #pragma unroll 4
    for (int n = 0; n < NLM; n++) {
        float4 a = sA[n];                 // LDS broadcast (same addr all lanes)
        float4 v = sV[n];
        float t  = fmaf(gx, a.x, fmaf(gy, a.y, gz * a.z));
        float d2 = g2 + a.w - 2.f * t;    // ||g-c||^2
        float e  = __expf(-200.f * d2);   // exp(-d2/ALPHA), ALPHA=0.005
        S  += e;
        vx = fmaf(e, v.x, vx);
        vy = fmaf(e, v.y, vy);
        vz = fmaf(e, v.z, vz);
    }
    const float inv = 1.01f / (S + 0.01f);   // (BETA+1)/(sum+BETA)
    C[b*OPS3 + g] = make_float4(vx*inv, vy*inv, vz*inv, 0.f);
}

__device__ __forceinline__ void axis_interp(int t, int& a0, int& a1, float& w) {
    // (t+0.5)*40/128 - 0.5, clamped at 0; indices clamped to 39
    float c = fmaxf(0.3125f * (float)t - 0.34375f, 0.f);
    float f = floorf(c);
    a0 = (int)f;
    a1 = min(a0 + 1, OPS - 1);
    w = c - f;
}

__device__ __forceinline__ float4 lerp4(float4 a, float4 b, float t) {
    return make_float4(a.x + t*(b.x - a.x),
                       a.y + t*(b.y - a.y),
                       a.z + t*(b.z - a.z),
                       0.f);
}

__global__ __launch_bounds__(256)
void warp_kernel(const float* __restrict__ mask, const float4* __restrict__ C,
                 float* __restrict__ out) {
    const int idx = blockIdx.x * 256 + threadIdx.x;  // 0 .. NB*DIM3-1
    const int k = idx & (DIM-1);
    const int j = (idx >> 7) & (DIM-1);
    const int i = (idx >> 14) & (DIM-1);
    const int b = idx >> 21;

    int i0,i1,j0,j1,k0,k1; float ti,tj,tk;
    axis_interp(i, i0, i1, ti);   // p-axis
    axis_interp(j, j0, j1, tj);   // q-axis
    axis_interp(k, k0, k1, tk);   // r-axis

    const float4* Cb = C + b*OPS3;
    const int s_p = OPS*OPS, s_q = OPS;
    float4 c00 = lerp4(Cb[i0*s_p + j0*s_q + k0], Cb[i0*s_p + j0*s_q + k1], tk);
    float4 c01 = lerp4(Cb[i0*s_p + j1*s_q + k0], Cb[i0*s_p + j1*s_q + k1], tk);
    float4 c10 = lerp4(Cb[i1*s_p + j0*s_q + k0], Cb[i1*s_p + j0*s_q + k1], tk);
    float4 c11 = lerp4(Cb[i1*s_p + j1*s_q + k0], Cb[i1*s_p + j1*s_q + k1], tk);
    float4 c0  = lerp4(c00, c01, tj);
    float4 c1  = lerp4(c10, c11, tj);
    float4 fl  = lerp4(c0, c1, ti);   // flow channels 0,1,2

    const float s127 = 2.f / (DIM - 1);
    float x = -1.f + s127 * (float)k + fl.x;
    float y = -1.f + s127 * (float)j + fl.y;
    float z = -1.f + s127 * (float)i + fl.z;

    // align_corners=False pixel coords
    float px = ((x + 1.f) * (float)DIM - 1.f) * 0.5f;
    float py = ((y + 1.f) * (float)DIM - 1.f) * 0.5f;
    float pz = ((z + 1.f) * (float)DIM - 1.f) * 0.5f;

    float xf = floorf(px), yf = floorf(py), zf = floorf(pz);
    int   x0 = (int)xf,    y0 = (int)yf,    z0 = (int)zf;
    float ax = px - xf,    ay = py - yf,    az = pz - zf;

    const float* M = mask + b * DIM3;
    float acc = 0.f;
    #pragma unroll
    for (int dz = 0; dz < 2; dz++) {
        int zi = z0 + dz;
        bool zin = (unsigned)zi < (unsigned)DIM;
        int zc = min(max(zi, 0), DIM-1);
        float wz = dz ? az : 1.f - az;
        #pragma unroll
        for (int dy = 0; dy < 2; dy++) {
            int yi = y0 + dy;
            bool yin = (unsigned)yi < (unsigned)DIM;
            int yc = min(max(yi, 0), DIM-1);
            float wy = dy ? ay : 1.f - ay;
            #pragma unroll
            for (int dx = 0; dx < 2; dx++) {
                int xi = x0 + dx;
                bool xin = (unsigned)xi < (unsigned)DIM;
                int xc = min(max(xi, 0), DIM-1);
                float wx = dx ? ax : 1.f - ax;
                float v = (zin && yin && xin) ? M[(zc*DIM + yc)*DIM + xc] : 0.f;
                acc = fmaf(v, wz*wy*wx, acc);
            }
        }
    }
    out[idx] = acc;
}

extern "C" void kernel_launch(void* const* d_in, const int* in_sizes, int n_in,
                              void* d_out, int out_size, void* d_ws, size_t ws_size,
                              hipStream_t stream) {
    const float* mask   = (const float*)d_in[0];   // (2,1,128,128,128)
    const float* coords = (const float*)d_in[1];   // (2,1024,3)
    const float* offs   = (const float*)d_in[2];   // (2,1024,3)
    float* out = (float*)d_out;

    char* ws = (char*)d_ws;
    float4* A      = (float4*)(ws);                    // NB*NLM
    float4* V      = (float4*)(ws + 32768);            // NB*NLM
    float4* coarse = (float4*)(ws + 65536);            // NB*OPS3

    prep_kernel<<<(NB*NLM + 255)/256, 256, 0, stream>>>(coords, offs, A, V);

    dim3 g1(OPS3/128, NB);
    coarse_kernel<<<g1, 128, 0, stream>>>(A, V, coarse);

    warp_kernel<<<(NB*DIM3)/256, 256, 0, stream>>>(mask, coarse, out);
}

// Round 2
// 152.915 us; speedup vs baseline: 1.1020x; 1.1020x over previous
//
#include <hip/hip_runtime.h>
#include <math.h>

#define NLM   1024      // landmarks per batch
#define NB    2         // batches
#define OPS   40        // coarse grid size per axis
#define DIM   128       // output volume size per axis
#define OPS3  (OPS*OPS*OPS)
#define DIM3  (DIM*DIM*DIM)

#define CPT   8         // cells per thread
#define NCHUNK 8        // landmark chunks (blockDim.y)
#define LPC   (NLM/NCHUNK)   // landmarks per chunk = 128

// exp(-d2/ALPHA) = exp2(K2*d2), K2 = -1/(ALPHA*ln2); M2 = -2*K2
#define K2f  (-288.5390081777927f)
#define M2f  ( 577.0780163555854f)

// ---------------------------------------------------------------------------
// ws layout:
//   A      : float4[NB*NLM]   @ 0       (cx,cy,cz,|c|^2)
//   V      : float4[NB*NLM]   @ 32768   (vx,vy,vz,0)
//   coarse : float4[NB*OPS3]  @ 65536   (flow0,flow1,flow2,0)
// total = 65536 + 2*64000*16 = 2,113,536 bytes
// ---------------------------------------------------------------------------

__device__ __forceinline__ float fexp2(float x) {
#if __has_builtin(__builtin_amdgcn_exp2f)
    return __builtin_amdgcn_exp2f(x);   // single v_exp_f32
#else
    return exp2f(x);
#endif
}

__global__ __launch_bounds__(256)
void prep_kernel(const float* __restrict__ coords, const float* __restrict__ offs,
                 float4* __restrict__ A, float4* __restrict__ V) {
    int i = blockIdx.x * blockDim.x + threadIdx.x;   // b*NLM + n
    if (i >= NB * NLM) return;
    float ox = offs[3*i+0], oy = offs[3*i+1], oz = offs[3*i+2];
    float cx = coords[3*i+0] + ox;
    float cy = coords[3*i+1] + oy;
    float cz = coords[3*i+2] + oz;
    A[i] = make_float4(cx, cy, cz, cx*cx + cy*cy + cz*cz);
    V[i] = make_float4(-ox, -oy, -oz, 0.f);
}

// Block (64,8): 512 consecutive coarse cells, thread (x,y) handles cells
// base + c*64 + x for c in 0..7, landmark chunk y (128 landmarks).
// In-block reduction across the 8 chunk-rows, then normalize+store.
__global__ __launch_bounds__(512, 2)
void coarse_kernel(const float4* __restrict__ A, const float4* __restrict__ V,
                   float4* __restrict__ C) {
    __shared__ float4 sA[NLM];       // 16 KB
    __shared__ float4 sV[NLM];       // 16 KB
    __shared__ float4 red[512];      // 8 KB reduction scratch

    const int tx = threadIdx.x;      // 0..63
    const int ty = threadIdx.y;      // 0..7 (chunk)
    const int tid = ty * 64 + tx;    // 0..511
    const int b = blockIdx.y;
    const int base = blockIdx.x * 512;   // first cell of this block

    // cooperative stage of all 1024 landmarks
    sA[tid]       = A[b*NLM + tid];
    sA[tid + 512] = A[b*NLM + tid + 512];
    sV[tid]       = V[b*NLM + tid];
    sV[tid + 512] = V[b*NLM + tid + 512];

    // per-cell constants (registers)
    float gx[CPT], gy[CPT], gz[CPT], h[CPT];
    const float step = 2.f / (OPS - 1);
    #pragma unroll
    for (int c = 0; c < CPT; ++c) {
        int g = base + c*64 + tx;
        int p = g / (OPS*OPS);
        int q = (g / OPS) % OPS;
        int r = g % OPS;
        gx[c] = -1.f + step * r;     // component 0
        gy[c] = -1.f + step * q;     // component 1
        gz[c] = -1.f + step * p;     // component 2
        h[c]  = K2f * (gx[c]*gx[c] + gy[c]*gy[c] + gz[c]*gz[c]);  // K2*|g|^2
    }

    float4 acc[CPT];
    #pragma unroll
    for (int c = 0; c < CPT; ++c) acc[c] = make_float4(0.f, 0.f, 0.f, 0.f);

    __syncthreads();

    const float4* sAy = &sA[ty * LPC];
    const float4* sVy = &sV[ty * LPC];

    #pragma unroll 2
    for (int n = 0; n < LPC; ++n) {
        float4 a = sAy[n];           // LDS broadcast within wave
        float4 v = sVy[n];
        float paw = K2f * a.w;       // shared across the 8 cells
        #pragma unroll
        for (int c = 0; c < CPT; ++c) {
            float u   = fmaf(gx[c], a.x, fmaf(gy[c], a.y, gz[c] * a.z));
            float arg = fmaf(M2f, u, h[c] + paw);   // K2*(|g|^2+|c|^2-2 g.c)
            float e   = fexp2(arg);
            acc[c].x += e;
            acc[c].y  = fmaf(e, v.x, acc[c].y);
            acc[c].z  = fmaf(e, v.y, acc[c].z);
            acc[c].w  = fmaf(e, v.z, acc[c].w);
        }
    }

    // reduce the 8 chunk-rows per cell, normalize, store
    float4* Cb = (float4*)(C + b*OPS3 + base);
    #pragma unroll
    for (int c = 0; c < CPT; ++c) {
        __syncthreads();
        red[tid] = acc[c];
        __syncthreads();
        if (ty == 0) {
            float4 s = red[tx];
            #pragma unroll
            for (int r2 = 1; r2 < NCHUNK; ++r2) {
                float4 t = red[r2*64 + tx];
                s.x += t.x; s.y += t.y; s.z += t.z; s.w += t.w;
            }
            float inv = 1.01f / (s.x + 0.01f);   // (BETA+1)/(sum+BETA)
            Cb[c*64 + tx] = make_float4(s.y*inv, s.z*inv, s.w*inv, 0.f);
        }
    }
}

__device__ __forceinline__ void axis_interp(int t, int& a0, int& a1, float& w) {
    // (t+0.5)*40/128 - 0.5, clamped at 0; indices clamped to 39
    float c = fmaxf(0.3125f * (float)t - 0.34375f, 0.f);
    float f = floorf(c);
    a0 = (int)f;
    a1 = min(a0 + 1, OPS - 1);
    w = c - f;
}

__device__ __forceinline__ float4 lerp4(float4 a, float4 b, float t) {
    return make_float4(a.x + t*(b.x - a.x),
                       a.y + t*(b.y - a.y),
                       a.z + t*(b.z - a.z),
                       0.f);
}

__global__ __launch_bounds__(256)
void warp_kernel(const float* __restrict__ mask, const float4* __restrict__ C,
                 float* __restrict__ out) {
    const int idx = blockIdx.x * 256 + threadIdx.x;  // 0 .. NB*DIM3-1
    const int k = idx & (DIM-1);
    const int j = (idx >> 7) & (DIM-1);
    const int i = (idx >> 14) & (DIM-1);
    const int b = idx >> 21;

    int i0,i1,j0,j1,k0,k1; float ti,tj,tk;
    axis_interp(i, i0, i1, ti);   // p-axis
    axis_interp(j, j0, j1, tj);   // q-axis
    axis_interp(k, k0, k1, tk);   // r-axis

    const float4* Cb = C + b*OPS3;
    const int s_p = OPS*OPS, s_q = OPS;
    float4 c00 = lerp4(Cb[i0*s_p + j0*s_q + k0], Cb[i0*s_p + j0*s_q + k1], tk);
    float4 c01 = lerp4(Cb[i0*s_p + j1*s_q + k0], Cb[i0*s_p + j1*s_q + k1], tk);
    float4 c10 = lerp4(Cb[i1*s_p + j0*s_q + k0], Cb[i1*s_p + j0*s_q + k1], tk);
    float4 c11 = lerp4(Cb[i1*s_p + j1*s_q + k0], Cb[i1*s_p + j1*s_q + k1], tk);
    float4 c0  = lerp4(c00, c01, tj);
    float4 c1  = lerp4(c10, c11, tj);
    float4 fl  = lerp4(c0, c1, ti);   // flow channels 0,1,2

    const float s127 = 2.f / (DIM - 1);
    float x = -1.f + s127 * (float)k + fl.x;
    float y = -1.f + s127 * (float)j + fl.y;
    float z = -1.f + s127 * (float)i + fl.z;

    // align_corners=False pixel coords
    float px = ((x + 1.f) * (float)DIM - 1.f) * 0.5f;
    float py = ((y + 1.f) * (float)DIM - 1.f) * 0.5f;
    float pz = ((z + 1.f) * (float)DIM - 1.f) * 0.5f;

    float xf = floorf(px), yf = floorf(py), zf = floorf(pz);
    int   x0 = (int)xf,    y0 = (int)yf,    z0 = (int)zf;
    float ax = px - xf,    ay = py - yf,    az = pz - zf;

    const float* M = mask + b * DIM3;
    float acc = 0.f;
    #pragma unroll
    for (int dz = 0; dz < 2; dz++) {
        int zi = z0 + dz;
        bool zin = (unsigned)zi < (unsigned)DIM;
        int zc = min(max(zi, 0), DIM-1);
        float wz = dz ? az : 1.f - az;
        #pragma unroll
        for (int dy = 0; dy < 2; dy++) {
            int yi = y0 + dy;
            bool yin = (unsigned)yi < (unsigned)DIM;
            int yc = min(max(yi, 0), DIM-1);
            float wy = dy ? ay : 1.f - ay;
            #pragma unroll
            for (int dx = 0; dx < 2; dx++) {
                int xi = x0 + dx;
                bool xin = (unsigned)xi < (unsigned)DIM;
                int xc = min(max(xi, 0), DIM-1);
                float wx = dx ? ax : 1.f - ax;
                float v = (zin && yin && xin) ? M[(zc*DIM + yc)*DIM + xc] : 0.f;
                acc = fmaf(v, wz*wy*wx, acc);
            }
        }
    }
    out[idx] = acc;
}

extern "C" void kernel_launch(void* const* d_in, const int* in_sizes, int n_in,
                              void* d_out, int out_size, void* d_ws, size_t ws_size,
                              hipStream_t stream) {
    const float* mask   = (const float*)d_in[0];   // (2,1,128,128,128)
    const float* coords = (const float*)d_in[1];   // (2,1024,3)
    const float* offs   = (const float*)d_in[2];   // (2,1024,3)
    float* out = (float*)d_out;

    char* ws = (char*)d_ws;
    float4* A      = (float4*)(ws);                    // NB*NLM
    float4* V      = (float4*)(ws + 32768);            // NB*NLM
    float4* coarse = (float4*)(ws + 65536);            // NB*OPS3

    prep_kernel<<<(NB*NLM + 255)/256, 256, 0, stream>>>(coords, offs, A, V);

    dim3 g1(OPS3/512, NB);                             // 125 x 2 blocks
    coarse_kernel<<<g1, dim3(64, NCHUNK), 0, stream>>>(A, V, coarse);

    warp_kernel<<<(NB*DIM3)/256, 256, 0, stream>>>(mask, coarse, out);
}

// Round 3
// 145.577 us; speedup vs baseline: 1.1576x; 1.0504x over previous
//
#include <hip/hip_runtime.h>
#include <math.h>

#define NLM   1024      // landmarks per batch
#define NB    2         // batches
#define OPS   40        // coarse grid size per axis
#define DIM   128       // output volume size per axis
#define OPS3  (OPS*OPS*OPS)
#define DIM3  (DIM*DIM*DIM)

#define CPT   8         // cells per thread (coarse kernel)
#define NCHUNK 8        // landmark chunks (blockDim.y)
#define LPC   (NLM/NCHUNK)   // landmarks per chunk = 128

// exp(-d2/ALPHA) = exp2(K2*d2), K2 = -1/(ALPHA*ln2); M2 = -2*K2
#define K2f  (-288.5390081777927f)
#define M2f  ( 577.0780163555854f)

// ---------------------------------------------------------------------------
// ws layout:
//   A      : float4[NB*NLM]   @ 0       (cx,cy,cz,|c|^2)
//   V      : float4[NB*NLM]   @ 32768   (vx,vy,vz,0)
//   coarse : float4[NB*OPS3]  @ 65536   (flow0,flow1,flow2,0)
// total = 65536 + 2*64000*16 = 2,113,536 bytes
// ---------------------------------------------------------------------------

__device__ __forceinline__ float fexp2(float x) {
#if __has_builtin(__builtin_amdgcn_exp2f)
    return __builtin_amdgcn_exp2f(x);   // single v_exp_f32
#else
    return exp2f(x);
#endif
}

__global__ __launch_bounds__(256)
void prep_kernel(const float* __restrict__ coords, const float* __restrict__ offs,
                 float4* __restrict__ A, float4* __restrict__ V) {
    int i = blockIdx.x * blockDim.x + threadIdx.x;   // b*NLM + n
    if (i >= NB * NLM) return;
    float ox = offs[3*i+0], oy = offs[3*i+1], oz = offs[3*i+2];
    float cx = coords[3*i+0] + ox;
    float cy = coords[3*i+1] + oy;
    float cz = coords[3*i+2] + oz;
    A[i] = make_float4(cx, cy, cz, cx*cx + cy*cy + cz*cz);
    V[i] = make_float4(-ox, -oy, -oz, 0.f);
}

// Block (64,8): 512 consecutive coarse cells, thread (x,y) handles cells
// base + c*64 + x for c in 0..7, landmark chunk y (128 landmarks).
__global__ __launch_bounds__(512, 2)
void coarse_kernel(const float4* __restrict__ A, const float4* __restrict__ V,
                   float4* __restrict__ C) {
    __shared__ float4 sA[NLM];       // 16 KB
    __shared__ float4 sV[NLM];       // 16 KB
    __shared__ float4 red[512];      // 8 KB reduction scratch

    const int tx = threadIdx.x;      // 0..63
    const int ty = threadIdx.y;      // 0..7 (chunk)
    const int tid = ty * 64 + tx;    // 0..511
    const int b = blockIdx.y;
    const int base = blockIdx.x * 512;   // first cell of this block

    sA[tid]       = A[b*NLM + tid];
    sA[tid + 512] = A[b*NLM + tid + 512];
    sV[tid]       = V[b*NLM + tid];
    sV[tid + 512] = V[b*NLM + tid + 512];

    float gx[CPT], gy[CPT], gz[CPT], h[CPT];
    const float step = 2.f / (OPS - 1);
    #pragma unroll
    for (int c = 0; c < CPT; ++c) {
        int g = base + c*64 + tx;
        int p = g / (OPS*OPS);
        int q = (g / OPS) % OPS;
        int r = g % OPS;
        gx[c] = -1.f + step * r;
        gy[c] = -1.f + step * q;
        gz[c] = -1.f + step * p;
        h[c]  = K2f * (gx[c]*gx[c] + gy[c]*gy[c] + gz[c]*gz[c]);
    }

    float4 acc[CPT];
    #pragma unroll
    for (int c = 0; c < CPT; ++c) acc[c] = make_float4(0.f, 0.f, 0.f, 0.f);

    __syncthreads();

    const float4* sAy = &sA[ty * LPC];
    const float4* sVy = &sV[ty * LPC];

    #pragma unroll 2
    for (int n = 0; n < LPC; ++n) {
        float4 a = sAy[n];
        float4 v = sVy[n];
        float paw = K2f * a.w;
        #pragma unroll
        for (int c = 0; c < CPT; ++c) {
            float u   = fmaf(gx[c], a.x, fmaf(gy[c], a.y, gz[c] * a.z));
            float arg = fmaf(M2f, u, h[c] + paw);
            float e   = fexp2(arg);
            acc[c].x += e;
            acc[c].y  = fmaf(e, v.x, acc[c].y);
            acc[c].z  = fmaf(e, v.y, acc[c].z);
            acc[c].w  = fmaf(e, v.z, acc[c].w);
        }
    }

    float4* Cb = (float4*)(C + b*OPS3 + base);
    #pragma unroll
    for (int c = 0; c < CPT; ++c) {
        __syncthreads();
        red[tid] = acc[c];
        __syncthreads();
        if (ty == 0) {
            float4 s = red[tx];
            #pragma unroll
            for (int r2 = 1; r2 < NCHUNK; ++r2) {
                float4 t = red[r2*64 + tx];
                s.x += t.x; s.y += t.y; s.z += t.z; s.w += t.w;
            }
            float inv = 1.01f / (s.x + 0.01f);
            Cb[c*64 + tx] = make_float4(s.y*inv, s.z*inv, s.w*inv, 0.f);
        }
    }
}

__device__ __forceinline__ void axis_interp(int t, int& a0, int& a1, float& w) {
    // (t+0.5)*40/128 - 0.5, clamped at 0; indices clamped to 39
    float c = fmaxf(0.3125f * (float)t - 0.34375f, 0.f);
    float f = floorf(c);
    a0 = (int)f;
    a1 = min(a0 + 1, OPS - 1);
    w = c - f;
}

__device__ __forceinline__ float4 lerp4(float4 a, float4 b, float t) {
    return make_float4(a.x + t*(b.x - a.x),
                       a.y + t*(b.y - a.y),
                       a.z + t*(b.z - a.z),
                       0.f);
}

// One block per (b,i,j) output k-line. Threads 0..39 hoist the (p,q)-bilinear
// of the coarse field into a 40-entry LDS line; all 128 threads then do one
// k-lerp + the 8-tap mask gather.
__global__ __launch_bounds__(128)
void warp_kernel(const float* __restrict__ mask, const float4* __restrict__ C,
                 float* __restrict__ out) {
    __shared__ float4 sF[OPS];

    const int blk = blockIdx.x;            // b*DIM*DIM + i*DIM + j
    const int j = blk & (DIM-1);           // H index
    const int i = (blk >> 7) & (DIM-1);    // D index
    const int b = blk >> 14;

    int i0,i1,j0,j1; float ti,tj;
    axis_interp(i, i0, i1, ti);   // p-axis
    axis_interp(j, j0, j1, tj);   // q-axis

    const float4* Cb = C + b*OPS3;
    const int t = threadIdx.x;
    if (t < OPS) {
        const int r = t;
        float4 c00 = Cb[(i0*OPS + j0)*OPS + r];
        float4 c01 = Cb[(i0*OPS + j1)*OPS + r];
        float4 c10 = Cb[(i1*OPS + j0)*OPS + r];
        float4 c11 = Cb[(i1*OPS + j1)*OPS + r];
        float4 c0  = lerp4(c00, c01, tj);
        float4 c1  = lerp4(c10, c11, tj);
        sF[r] = lerp4(c0, c1, ti);
    }
    __syncthreads();

    const int k = t;                       // W index
    int k0,k1; float tk;
    axis_interp(k, k0, k1, tk);
    float4 fl = lerp4(sF[k0], sF[k1], tk); // flow channels 0,1,2

    const float s127 = 2.f / (DIM - 1);
    float x = -1.f + s127 * (float)k + fl.x;
    float y = -1.f + s127 * (float)j + fl.y;
    float z = -1.f + s127 * (float)i + fl.z;

    // align_corners=False pixel coords
    float px = ((x + 1.f) * (float)DIM - 1.f) * 0.5f;
    float py = ((y + 1.f) * (float)DIM - 1.f) * 0.5f;
    float pz = ((z + 1.f) * (float)DIM - 1.f) * 0.5f;

    float xf = floorf(px), yf = floorf(py), zf = floorf(pz);
    int   x0 = (int)xf,    y0 = (int)yf,    z0 = (int)zf;
    float ax = px - xf,    ay = py - yf,    az = pz - zf;

    const float* M = mask + b * DIM3;
    float acc = 0.f;
    #pragma unroll
    for (int dz = 0; dz < 2; dz++) {
        int zi = z0 + dz;
        bool zin = (unsigned)zi < (unsigned)DIM;
        int zc = min(max(zi, 0), DIM-1);
        float wz = dz ? az : 1.f - az;
        #pragma unroll
        for (int dy = 0; dy < 2; dy++) {
            int yi = y0 + dy;
            bool yin = (unsigned)yi < (unsigned)DIM;
            int yc = min(max(yi, 0), DIM-1);
            float wy = dy ? ay : 1.f - ay;
            #pragma unroll
            for (int dx = 0; dx < 2; dx++) {
                int xi = x0 + dx;
                bool xin = (unsigned)xi < (unsigned)DIM;
                int xc = min(max(xi, 0), DIM-1);
                float wx = dx ? ax : 1.f - ax;
                float v = (zin && yin && xin) ? M[(zc*DIM + yc)*DIM + xc] : 0.f;
                acc = fmaf(v, wz*wy*wx, acc);
            }
        }
    }
    out[(blk << 7) | k] = acc;
}

extern "C" void kernel_launch(void* const* d_in, const int* in_sizes, int n_in,
                              void* d_out, int out_size, void* d_ws, size_t ws_size,
                              hipStream_t stream) {
    const float* mask   = (const float*)d_in[0];   // (2,1,128,128,128)
    const float* coords = (const float*)d_in[1];   // (2,1024,3)
    const float* offs   = (const float*)d_in[2];   // (2,1024,3)
    float* out = (float*)d_out;

    char* ws = (char*)d_ws;
    float4* A      = (float4*)(ws);                    // NB*NLM
    float4* V      = (float4*)(ws + 32768);            // NB*NLM
    float4* coarse = (float4*)(ws + 65536);            // NB*OPS3

    prep_kernel<<<(NB*NLM + 255)/256, 256, 0, stream>>>(coords, offs, A, V);

    dim3 g1(OPS3/512, NB);                             // 125 x 2 blocks
    coarse_kernel<<<g1, dim3(64, NCHUNK), 0, stream>>>(A, V, coarse);

    warp_kernel<<<NB*DIM*DIM, 128, 0, stream>>>(mask, coarse, out);
}

// Round 4
// 122.189 us; speedup vs baseline: 1.3791x; 1.1914x over previous
//
#include <hip/hip_runtime.h>
#include <math.h>

#define NLM   1024      // landmarks per batch
#define NB    2         // batches
#define OPS   40        // coarse grid size per axis
#define DIM   128       // output volume size per axis
#define OPS3  (OPS*OPS*OPS)
#define DIM3  (DIM*DIM*DIM)

#define TILE   8                 // coarse tile edge (cells)
#define NTILE  (OPS/TILE)        // 5
#define CPT    4                 // cells per thread (coarse)
#define MARGIN 0.30f             // exp2(-288.5*0.09) ~ 2e-8 -> negligible

// exp(-d2/ALPHA) = exp2(K2*d2), K2 = -1/(ALPHA*ln2); M2 = -2*K2
#define K2f  (-288.5390081777927f)
#define M2f  ( 577.0780163555854f)

// ws layout: coarse : float4[NB*OPS3] @ 0   (2,048,000 bytes)

__device__ __forceinline__ float fexp2(float x) {
#if __has_builtin(__builtin_amdgcn_exp2f)
    return __builtin_amdgcn_exp2f(x);   // single v_exp_f32
#else
    return exp2f(x);
#endif
}

// One block per 8x8x8 coarse-cell tile (125 tiles x 2 batches).
// Phase 1: compact the ~113 landmarks inside the tile's +-MARGIN box into LDS
//          (computing A=(c, K2*|c|^2) and V=-offset on the fly; prep fused).
// Phase 2: each of 128 threads accumulates 4 cells over the compacted list
//          (LDS broadcast reads amortized over 4 register-resident cells).
__global__ __launch_bounds__(128)
void coarse_kernel(const float* __restrict__ coords, const float* __restrict__ offs,
                   float4* __restrict__ C) {
    __shared__ float4 sA[NLM];       // 16 KB (worst case all landmarks in box)
    __shared__ float4 sV[NLM];       // 16 KB
    __shared__ int sCnt;

    const int t = threadIdx.x;       // 0..127
    const int b = blockIdx.y;
    const int tile = blockIdx.x;     // 0..124
    const int tp = tile / (NTILE*NTILE);
    const int tq = (tile / NTILE) % NTILE;
    const int tr = tile % NTILE;

    const float step = 2.f / (OPS - 1);
    const float bx0 = -1.f + step * (tr*TILE)          - MARGIN;
    const float bx1 = -1.f + step * (tr*TILE + TILE-1) + MARGIN;
    const float by0 = -1.f + step * (tq*TILE)          - MARGIN;
    const float by1 = -1.f + step * (tq*TILE + TILE-1) + MARGIN;
    const float bz0 = -1.f + step * (tp*TILE)          - MARGIN;
    const float bz1 = -1.f + step * (tp*TILE + TILE-1) + MARGIN;

    if (t == 0) sCnt = 0;
    __syncthreads();

    for (int n = t; n < NLM; n += 128) {
        const float* cp = coords + (b*NLM + n)*3;
        const float* op = offs   + (b*NLM + n)*3;
        float ox = op[0], oy = op[1], oz = op[2];
        float cx = cp[0] + ox, cy = cp[1] + oy, cz = cp[2] + oz;
        if (cx >= bx0 && cx <= bx1 && cy >= by0 && cy <= by1 &&
            cz >= bz0 && cz <= bz1) {
            int idx = atomicAdd(&sCnt, 1);
            sA[idx] = make_float4(cx, cy, cz, K2f*(cx*cx + cy*cy + cz*cz));
            sV[idx] = make_float4(-ox, -oy, -oz, 0.f);
        }
    }
    __syncthreads();
    const int cnt = sCnt;

    // per-cell constants; cell local index = c*128 + t -> (lp,lq,lr)
    float gx[CPT], gy[CPT], gz[CPT], h[CPT];
    #pragma unroll
    for (int c = 0; c < CPT; ++c) {
        int local = c*128 + t;
        int lp = local >> 6, lq = (local >> 3) & 7, lr = local & 7;
        gx[c] = -1.f + step * (tr*TILE + lr);   // component 0
        gy[c] = -1.f + step * (tq*TILE + lq);   // component 1
        gz[c] = -1.f + step * (tp*TILE + lp);   // component 2
        h[c]  = K2f * (gx[c]*gx[c] + gy[c]*gy[c] + gz[c]*gz[c]);
    }

    float4 acc[CPT];
    #pragma unroll
    for (int c = 0; c < CPT; ++c) acc[c] = make_float4(0.f, 0.f, 0.f, 0.f);

    for (int n = 0; n < cnt; ++n) {
        float4 a = sA[n];            // LDS broadcast
        float4 v = sV[n];
        #pragma unroll
        for (int c = 0; c < CPT; ++c) {
            float u   = fmaf(gx[c], a.x, fmaf(gy[c], a.y, gz[c]*a.z));
            float arg = fmaf(M2f, u, h[c] + a.w);   // K2*||g-c||^2
            float e   = fexp2(arg);
            acc[c].x += e;
            acc[c].y  = fmaf(e, v.x, acc[c].y);
            acc[c].z  = fmaf(e, v.y, acc[c].z);
            acc[c].w  = fmaf(e, v.z, acc[c].w);
        }
    }

    #pragma unroll
    for (int c = 0; c < CPT; ++c) {
        int local = c*128 + t;
        int lp = local >> 6, lq = (local >> 3) & 7, lr = local & 7;
        int p = tp*TILE + lp, q = tq*TILE + lq, r = tr*TILE + lr;
        float inv = 1.01f / (acc[c].x + 0.01f);     // (BETA+1)/(sum+BETA)
        C[b*OPS3 + (p*OPS + q)*OPS + r] =
            make_float4(acc[c].y*inv, acc[c].z*inv, acc[c].w*inv, 0.f);
    }
}

__device__ __forceinline__ void axis_interp(int t, int& a0, int& a1, float& w) {
    // (t+0.5)*40/128 - 0.5, clamped at 0; indices clamped to 39
    float c = fmaxf(0.3125f * (float)t - 0.34375f, 0.f);
    float f = floorf(c);
    a0 = (int)f;
    a1 = min(a0 + 1, OPS - 1);
    w = c - f;
}

__device__ __forceinline__ float4 lerp4(float4 a, float4 b, float t) {
    return make_float4(a.x + t*(b.x - a.x),
                       a.y + t*(b.y - a.y),
                       a.z + t*(b.z - a.z),
                       0.f);
}

// One wave (64 threads) per (b,i,j) k-line; each thread handles k and k+64.
// XCD slab swizzle: blk -> line = (blk&7)*4096 + (blk>>3) gives each
// round-robin XCD slot a contiguous 32-i slab (~3.5 MB of touched z-planes,
// fits the 4 MB per-XCD L2).
__global__ __launch_bounds__(64)
void warp_kernel(const float* __restrict__ mask, const float4* __restrict__ C,
                 float* __restrict__ out) {
    __shared__ float4 sF[OPS];

    const int blk  = blockIdx.x;
    const int line = ((blk & 7) << 12) + (blk >> 3);   // b*DIM*DIM + i*DIM + j
    const int j = line & (DIM-1);
    const int i = (line >> 7) & (DIM-1);
    const int b = line >> 14;

    int i0,i1,j0,j1; float ti,tj;
    axis_interp(i, i0, i1, ti);
    axis_interp(j, j0, j1, tj);

    const float4* Cb = C + b*OPS3;
    const int t = threadIdx.x;
    if (t < OPS) {
        float4 c00 = Cb[(i0*OPS + j0)*OPS + t];
        float4 c01 = Cb[(i0*OPS + j1)*OPS + t];
        float4 c10 = Cb[(i1*OPS + j0)*OPS + t];
        float4 c11 = Cb[(i1*OPS + j1)*OPS + t];
        sF[t] = lerp4(lerp4(c00, c01, tj), lerp4(c10, c11, tj), ti);
    }
    __syncthreads();

    const float* M = mask + b * DIM3;
    const float s127 = 2.f / (DIM - 1);
    const float yb = -1.f + s127 * (float)j;
    const float zb = -1.f + s127 * (float)i;

    float res[2];
    #pragma unroll
    for (int c = 0; c < 2; ++c) {
        const int k = t + 64*c;
        int k0,k1; float tk;
        axis_interp(k, k0, k1, tk);
        float4 fl = lerp4(sF[k0], sF[k1], tk);

        float x = -1.f + s127 * (float)k + fl.x;
        float y = yb + fl.y;
        float z = zb + fl.z;

        float px = ((x + 1.f) * (float)DIM - 1.f) * 0.5f;
        float py = ((y + 1.f) * (float)DIM - 1.f) * 0.5f;
        float pz = ((z + 1.f) * (float)DIM - 1.f) * 0.5f;

        float xf = floorf(px), yf = floorf(py), zf = floorf(pz);
        int   x0 = (int)xf,    y0 = (int)yf,    z0 = (int)zf;
        float ax = px - xf,    ay = py - yf,    az = pz - zf;

        float acc = 0.f;
        #pragma unroll
        for (int dz = 0; dz < 2; dz++) {
            int zi = z0 + dz;
            bool zin = (unsigned)zi < (unsigned)DIM;
            int zc = min(max(zi, 0), DIM-1);
            float wz = dz ? az : 1.f - az;
            #pragma unroll
            for (int dy = 0; dy < 2; dy++) {
                int yi = y0 + dy;
                bool yin = (unsigned)yi < (unsigned)DIM;
                int yc = min(max(yi, 0), DIM-1);
                float wy = dy ? ay : 1.f - ay;
                #pragma unroll
                for (int dx = 0; dx < 2; dx++) {
                    int xi = x0 + dx;
                    bool xin = (unsigned)xi < (unsigned)DIM;
                    int xc = min(max(xi, 0), DIM-1);
                    float wx = dx ? ax : 1.f - ax;
                    float v = (zin && yin && xin) ? M[(zc*DIM + yc)*DIM + xc] : 0.f;
                    acc = fmaf(v, wz*wy*wx, acc);
                }
            }
        }
        res[c] = acc;
    }
    out[(line << 7) + t]      = res[0];
    out[(line << 7) + t + 64] = res[1];
}

extern "C" void kernel_launch(void* const* d_in, const int* in_sizes, int n_in,
                              void* d_out, int out_size, void* d_ws, size_t ws_size,
                              hipStream_t stream) {
    const float* mask   = (const float*)d_in[0];   // (2,1,128,128,128)
    const float* coords = (const float*)d_in[1];   // (2,1024,3)
    const float* offs   = (const float*)d_in[2];   // (2,1024,3)
    float* out = (float*)d_out;

    float4* coarse = (float4*)d_ws;                // NB*OPS3 float4

    dim3 g1(NTILE*NTILE*NTILE, NB);                // 125 x 2 blocks
    coarse_kernel<<<g1, 128, 0, stream>>>(coords, offs, coarse);

    warp_kernel<<<NB*DIM*DIM, 64, 0, stream>>>(mask, coarse, out);
}

// Round 5
// 110.996 us; speedup vs baseline: 1.5182x; 1.1008x over previous
//
#include <hip/hip_runtime.h>
#include <math.h>

#define NLM   1024      // landmarks per batch
#define NB    2         // batches
#define OPS   40        // coarse grid size per axis
#define DIM   128       // output volume size per axis
#define OPS3  (OPS*OPS*OPS)
#define DIM3  (DIM*DIM*DIM)

#define TILE   8                 // coarse tile edge (cells)
#define NTILE  (OPS/TILE)        // 5
#define CPT    4                 // cells per thread (coarse)
#define MARGIN 0.30f             // exp2(-288.5*0.09) ~ 2e-8 -> negligible

// exp(-d2/ALPHA) = exp2(K2*d2), K2 = -1/(ALPHA*ln2); M2 = -2*K2
#define K2f  (-288.5390081777927f)
#define M2f  ( 577.0780163555854f)

// ws layout: coarse : float4[NB*OPS3] @ 0   (2,048,000 bytes)

__device__ __forceinline__ float fexp2(float x) {
#if __has_builtin(__builtin_amdgcn_exp2f)
    return __builtin_amdgcn_exp2f(x);   // single v_exp_f32
#else
    return exp2f(x);
#endif
}

// One block per 8x8x8 coarse-cell tile (125 tiles x 2 batches).
__global__ __launch_bounds__(128)
void coarse_kernel(const float* __restrict__ coords, const float* __restrict__ offs,
                   float4* __restrict__ C) {
    __shared__ float4 sA[NLM];
    __shared__ float4 sV[NLM];
    __shared__ int sCnt;

    const int t = threadIdx.x;       // 0..127
    const int b = blockIdx.y;
    const int tile = blockIdx.x;     // 0..124
    const int tp = tile / (NTILE*NTILE);
    const int tq = (tile / NTILE) % NTILE;
    const int tr = tile % NTILE;

    const float step = 2.f / (OPS - 1);
    const float bx0 = -1.f + step * (tr*TILE)          - MARGIN;
    const float bx1 = -1.f + step * (tr*TILE + TILE-1) + MARGIN;
    const float by0 = -1.f + step * (tq*TILE)          - MARGIN;
    const float by1 = -1.f + step * (tq*TILE + TILE-1) + MARGIN;
    const float bz0 = -1.f + step * (tp*TILE)          - MARGIN;
    const float bz1 = -1.f + step * (tp*TILE + TILE-1) + MARGIN;

    if (t == 0) sCnt = 0;
    __syncthreads();

    for (int n = t; n < NLM; n += 128) {
        const float* cp = coords + (b*NLM + n)*3;
        const float* op = offs   + (b*NLM + n)*3;
        float ox = op[0], oy = op[1], oz = op[2];
        float cx = cp[0] + ox, cy = cp[1] + oy, cz = cp[2] + oz;
        if (cx >= bx0 && cx <= bx1 && cy >= by0 && cy <= by1 &&
            cz >= bz0 && cz <= bz1) {
            int idx = atomicAdd(&sCnt, 1);
            sA[idx] = make_float4(cx, cy, cz, K2f*(cx*cx + cy*cy + cz*cz));
            sV[idx] = make_float4(-ox, -oy, -oz, 0.f);
        }
    }
    __syncthreads();
    const int cnt = sCnt;

    float gx[CPT], gy[CPT], gz[CPT], h[CPT];
    #pragma unroll
    for (int c = 0; c < CPT; ++c) {
        int local = c*128 + t;
        int lp = local >> 6, lq = (local >> 3) & 7, lr = local & 7;
        gx[c] = -1.f + step * (tr*TILE + lr);
        gy[c] = -1.f + step * (tq*TILE + lq);
        gz[c] = -1.f + step * (tp*TILE + lp);
        h[c]  = K2f * (gx[c]*gx[c] + gy[c]*gy[c] + gz[c]*gz[c]);
    }

    float4 acc[CPT];
    #pragma unroll
    for (int c = 0; c < CPT; ++c) acc[c] = make_float4(0.f, 0.f, 0.f, 0.f);

    for (int n = 0; n < cnt; ++n) {
        float4 a = sA[n];
        float4 v = sV[n];
        #pragma unroll
        for (int c = 0; c < CPT; ++c) {
            float u   = fmaf(gx[c], a.x, fmaf(gy[c], a.y, gz[c]*a.z));
            float arg = fmaf(M2f, u, h[c] + a.w);
            float e   = fexp2(arg);
            acc[c].x += e;
            acc[c].y  = fmaf(e, v.x, acc[c].y);
            acc[c].z  = fmaf(e, v.y, acc[c].z);
            acc[c].w  = fmaf(e, v.z, acc[c].w);
        }
    }

    #pragma unroll
    for (int c = 0; c < CPT; ++c) {
        int local = c*128 + t;
        int lp = local >> 6, lq = (local >> 3) & 7, lr = local & 7;
        int p = tp*TILE + lp, q = tq*TILE + lq, r = tr*TILE + lr;
        float inv = 1.01f / (acc[c].x + 0.01f);
        C[b*OPS3 + (p*OPS + q)*OPS + r] =
            make_float4(acc[c].y*inv, acc[c].z*inv, acc[c].w*inv, 0.f);
    }
}

__device__ __forceinline__ void axis_interp(int t, int& a0, int& a1, float& w) {
    float c = fmaxf(0.3125f * (float)t - 0.34375f, 0.f);
    float f = floorf(c);
    a0 = (int)f;
    a1 = min(a0 + 1, OPS - 1);
    w = c - f;
}

__device__ __forceinline__ float4 lerp4(float4 a, float4 b, float t) {
    return make_float4(a.x + t*(b.x - a.x),
                       a.y + t*(b.y - a.y),
                       a.z + t*(b.z - a.z),
                       0.f);
}

// Per-voxel sample coords. Returns base index and weights; fast = fully interior.
struct Samp { int rb; float ax, ay, az; bool fast; int x0, y0, z0; };

__device__ __forceinline__ Samp make_samp(float px, float py, float pz) {
    Samp s;
    float xf = floorf(px), yf = floorf(py), zf = floorf(pz);
    s.x0 = (int)xf; s.y0 = (int)yf; s.z0 = (int)zf;
    s.ax = px - xf; s.ay = py - yf; s.az = pz - zf;
    s.fast = ((unsigned)s.x0 < 127u) & ((unsigned)s.y0 < 127u) & ((unsigned)s.z0 < 127u);
    s.rb = (s.z0*DIM + s.y0)*DIM + s.x0;
    return s;
}

__device__ __forceinline__ float slow_gather(const float* __restrict__ M, const Samp& s) {
    float acc = 0.f;
    #pragma unroll
    for (int dz = 0; dz < 2; dz++) {
        int zi = s.z0 + dz;
        bool zin = (unsigned)zi < (unsigned)DIM;
        int zc = min(max(zi, 0), DIM-1);
        float wz = dz ? s.az : 1.f - s.az;
        #pragma unroll
        for (int dy = 0; dy < 2; dy++) {
            int yi = s.y0 + dy;
            bool yin = (unsigned)yi < (unsigned)DIM;
            int yc = min(max(yi, 0), DIM-1);
            float wy = dy ? s.ay : 1.f - s.ay;
            #pragma unroll
            for (int dx = 0; dx < 2; dx++) {
                int xi = s.x0 + dx;
                bool xin = (unsigned)xi < (unsigned)DIM;
                int xc = min(max(xi, 0), DIM-1);
                float wx = dx ? s.ax : 1.f - s.ax;
                float v = (zin && yin && xin) ? M[(zc*DIM + yc)*DIM + xc] : 0.f;
                acc = fmaf(v, wz*wy*wx, acc);
            }
        }
    }
    return acc;
}

__device__ __forceinline__ float tri8(float v000, float v001, float v010, float v011,
                                      float v100, float v101, float v110, float v111,
                                      float ax, float ay, float az) {
    float c00 = fmaf(ax, v001 - v000, v000);
    float c01 = fmaf(ax, v011 - v010, v010);
    float c10 = fmaf(ax, v101 - v100, v100);
    float c11 = fmaf(ax, v111 - v110, v110);
    float c0  = fmaf(ay, c01 - c00, c00);
    float c1  = fmaf(ay, c11 - c10, c10);
    return fmaf(az, c1 - c0, c0);
}

// 256-thread blocks = 4 waves; wave w handles one (b,i,j) k-line, each lane
// 2 voxels (k, k+64). XCD slab swizzle preserved from round 3 (g&7 slot ->
// contiguous 32-i slab). Interior fast path: one base index per voxel, 8
// loads at immediate offsets, no clamps/masks; both voxels' 16 loads in
// flight before accumulation.
__global__ __launch_bounds__(256)
void warp_kernel(const float* __restrict__ mask, const float4* __restrict__ C,
                 float* __restrict__ out) {
    __shared__ float4 sF[4][OPS];

    const int g = blockIdx.x;                       // 0..8191
    const int w = threadIdx.x >> 6;                 // wave 0..3
    const int lane = threadIdx.x & 63;
    const int line = ((g & 7) << 12) + ((g >> 3) << 2) + w;  // b*DIM*DIM+i*DIM+j
    const int j = line & (DIM-1);
    const int i = (line >> 7) & (DIM-1);
    const int b = line >> 14;

    int i0,i1,j0,j1; float ti,tj;
    axis_interp(i, i0, i1, ti);
    axis_interp(j, j0, j1, tj);

    const float4* Cb = C + b*OPS3;
    if (lane < OPS) {
        float4 c00 = Cb[(i0*OPS + j0)*OPS + lane];
        float4 c01 = Cb[(i0*OPS + j1)*OPS + lane];
        float4 c10 = Cb[(i1*OPS + j0)*OPS + lane];
        float4 c11 = Cb[(i1*OPS + j1)*OPS + lane];
        sF[w][lane] = lerp4(lerp4(c00, c01, tj), lerp4(c10, c11, tj), ti);
    }
    // no barrier: sF[w] is produced and consumed by wave w only (lockstep)

    const float* M = mask + b * DIM3;
    const float s127 = 2.f / (DIM - 1);
    const float yb = -1.f + s127 * (float)j;
    const float zb = -1.f + s127 * (float)i;

    Samp sp[2];
    #pragma unroll
    for (int c = 0; c < 2; ++c) {
        const int k = lane + 64*c;
        int k0,k1; float tk;
        axis_interp(k, k0, k1, tk);
        float4 fl = lerp4(sF[w][k0], sF[w][k1], tk);
        float x = -1.f + s127 * (float)k + fl.x;
        float y = yb + fl.y;
        float z = zb + fl.z;
        sp[c] = make_samp(((x + 1.f) * (float)DIM - 1.f) * 0.5f,
                          ((y + 1.f) * (float)DIM - 1.f) * 0.5f,
                          ((z + 1.f) * (float)DIM - 1.f) * 0.5f);
    }

    float res[2];
    if (sp[0].fast && sp[1].fast) {
        const int rb0 = sp[0].rb, rb1 = sp[1].rb;
        // voxel 0 taps
        float a000 = M[rb0], a001 = M[rb0+1];
        float a010 = M[rb0+DIM], a011 = M[rb0+DIM+1];
        float a100 = M[rb0+DIM*DIM], a101 = M[rb0+DIM*DIM+1];
        float a110 = M[rb0+DIM*DIM+DIM], a111 = M[rb0+DIM*DIM+DIM+1];
        // voxel 1 taps
        float b000 = M[rb1], b001 = M[rb1+1];
        float b010 = M[rb1+DIM], b011 = M[rb1+DIM+1];
        float b100 = M[rb1+DIM*DIM], b101 = M[rb1+DIM*DIM+1];
        float b110 = M[rb1+DIM*DIM+DIM], b111 = M[rb1+DIM*DIM+DIM+1];
        res[0] = tri8(a000,a001,a010,a011,a100,a101,a110,a111,
                      sp[0].ax, sp[0].ay, sp[0].az);
        res[1] = tri8(b000,b001,b010,b011,b100,b101,b110,b111,
                      sp[1].ax, sp[1].ay, sp[1].az);
    } else {
        res[0] = slow_gather(M, sp[0]);
        res[1] = slow_gather(M, sp[1]);
    }

    out[(line << 7) + lane]      = res[0];
    out[(line << 7) + lane + 64] = res[1];
}

extern "C" void kernel_launch(void* const* d_in, const int* in_sizes, int n_in,
                              void* d_out, int out_size, void* d_ws, size_t ws_size,
                              hipStream_t stream) {
    const float* mask   = (const float*)d_in[0];   // (2,1,128,128,128)
    const float* coords = (const float*)d_in[1];   // (2,1024,3)
    const float* offs   = (const float*)d_in[2];   // (2,1024,3)
    float* out = (float*)d_out;

    float4* coarse = (float4*)d_ws;                // NB*OPS3 float4

    dim3 g1(NTILE*NTILE*NTILE, NB);                // 125 x 2 blocks
    coarse_kernel<<<g1, 128, 0, stream>>>(coords, offs, coarse);

    warp_kernel<<<NB*DIM*DIM/4, 256, 0, stream>>>(mask, coarse, out);
}